// Round 6
// baseline (717.530 us; speedup 1.0000x reference)
//
#include <hip/hip_runtime.h>
#include <hip/hip_bf16.h>
#include <math.h>

// Problem constants
#define N_ROWS 512      // B*S
#define D_IN   512
#define E_EMB  256
#define H_DIM  512
#define G_DIM  2048
#define V_DIM  32000
#define IN_LD  1280     // Abuf row: [ x(512) | emb(256) | h(512) ]
#define KG     768      // per-step gates K: [emb|h]
#define K_STEPS 4
#define OOV_ID 1
#define TBK 64
#define EMB_SPLIT 50
#define EMB_CHUNK 640   // 50*640 = 32000
#define SEGSTRIDE 512   // stats row stride (500 used)

typedef __attribute__((ext_vector_type(4))) float f32x4;
typedef __attribute__((ext_vector_type(8))) short bf16x8;
typedef __attribute__((ext_vector_type(8))) _Float16 f16x8;

__device__ inline short f2b(float v) {
    __hip_bfloat16 h = __float2bfloat16(v);
    return *reinterpret_cast<short*>(&h);
}

// async global->LDS, 16B per lane; dest = ldsbase + lane*16 (wave-uniform base)
__device__ inline void gload_lds(const short* g, short* l) {
    __builtin_amdgcn_global_load_lds(
        (const __attribute__((address_space(1))) void*)g,
        (__attribute__((address_space(3))) void*)l, 16, 0, 0);
}

// ---------------------------------------------------------------------------
// MFMA GEMM: C(MxN) = A(MxK,bf16 rm) @ B(NxK,bf16 rm)^T [+bias]
// WR_ x WC_ waves (64*WR_*WC_ threads). global_load_lds staging, XOR-swizzled
// LDS chunks (proven 2-barrier structure; only tile/wave geometry templated).
// MODE 0: C = acc + bias[n]
// MODE 2: fused LSTM epilogue (requires WC_==1, WNT==64): the 4 N-fragments
//         of a thread are gates i,f,g,o of one j (Wg rows pre-reordered as
//         row' = (j>>4)*64 + gate*16 + (j&15)). Updates cstate, writes bf16 h
//         into hdst (Abuf h-region).
// MODE 3: split-K partial store: C[(bz*N_ROWS + m)*ldc + n] = acc  (no atomics)
// MODE 4: z = acc + bias stored as fp16 into C, plus per-64-col (max,sumexp)
//         stats partials (requires WNT==64).
// INITC 1: accumulator initialized from C (fp32, ldc) instead of 0; bias skipped.
template<int TBM, int TBN, int WR_, int WC_, int MODE, int INITC>
__global__ __launch_bounds__(WR_ * WC_ * 64) void k_gemm(
    const short* __restrict__ A, int lda,
    const short* __restrict__ B, int ldb,
    const float* __restrict__ bias,
    float* __restrict__ C, size_t ldc, int Kc,
    float2* __restrict__ stats,
    float* __restrict__ cstate, short* __restrict__ hdst)
{
    constexpr int NW = WR_ * WC_;
    constexpr int WMT = TBM / WR_, WNT = TBN / WC_;
    constexpr int WM = WMT / 16, WN = WNT / 16;
    __shared__ short As[TBM * 64];
    __shared__ short Bs[TBN * 64];
    const int tid = threadIdx.x;
    const int lane = tid & 63, wid = tid >> 6;
    const int wr = wid % WR_, wc = wid / WR_;
    const int quad = lane >> 4, l16 = lane & 15;
    const int m0 = blockIdx.y * TBM, n0 = blockIdx.x * TBN;
    const int kbase = blockIdx.z * Kc;
    // staging lane geometry: 8 rows/instr, 8 chunks of 8 bf16 per row, XOR swizzle
    const int lrow = lane >> 3;
    const int lsw  = ((lane & 7) ^ lrow) * 8;

    f32x4 acc[WM][WN];
    if constexpr (INITC) {
#pragma unroll
        for (int i = 0; i < WM; ++i)
#pragma unroll
            for (int j = 0; j < WN; ++j) {
                const int n = n0 + wc * WNT + j * 16 + l16;
#pragma unroll
                for (int r = 0; r < 4; ++r) {
                    const int m = m0 + wr * WMT + i * 16 + quad * 4 + r;
                    acc[i][j][r] = C[(size_t)m * ldc + n];
                }
            }
    } else {
#pragma unroll
        for (int i = 0; i < WM; ++i)
#pragma unroll
            for (int j = 0; j < WN; ++j)
#pragma unroll
                for (int r = 0; r < 4; ++r) acc[i][j][r] = 0.0f;
    }

    for (int kt = 0; kt < Kc; kt += TBK) {
        const int k0 = kbase + kt;
#pragma unroll
        for (int ch = wid; ch < TBM / 8; ch += NW)
            gload_lds(&A[(size_t)(m0 + ch * 8 + lrow) * lda + k0 + lsw], &As[ch * 512]);
#pragma unroll
        for (int ch = wid; ch < TBN / 8; ch += NW)
            gload_lds(&B[(size_t)(n0 + ch * 8 + lrow) * ldb + k0 + lsw], &Bs[ch * 512]);
        __syncthreads();
#pragma unroll
        for (int ks = 0; ks < 2; ++ks) {
            bf16x8 af[WM], bfv[WN];
#pragma unroll
            for (int i = 0; i < WM; ++i) {
                int rr = wr * WMT + i * 16 + l16;
                af[i] = *(const bf16x8*)&As[rr * 64 + (((ks * 4 + quad) ^ (l16 & 7)) * 8)];
            }
#pragma unroll
            for (int j = 0; j < WN; ++j) {
                int rr = wc * WNT + j * 16 + l16;
                bfv[j] = *(const bf16x8*)&Bs[rr * 64 + (((ks * 4 + quad) ^ (l16 & 7)) * 8)];
            }
#pragma unroll
            for (int i = 0; i < WM; ++i)
#pragma unroll
                for (int j = 0; j < WN; ++j)
                    acc[i][j] = __builtin_amdgcn_mfma_f32_16x16x32_bf16(af[i], bfv[j], acc[i][j], 0, 0, 0);
        }
        __syncthreads();
    }

    // epilogue. C frag layout: row = quad*4 + reg, col = l16
    if constexpr (MODE == 3) {
        float* Cp = C + (size_t)blockIdx.z * N_ROWS * ldc;
#pragma unroll
        for (int i = 0; i < WM; ++i)
#pragma unroll
            for (int j = 0; j < WN; ++j) {
                const int n = n0 + wc * WNT + j * 16 + l16;
#pragma unroll
                for (int r = 0; r < 4; ++r) {
                    const int m = m0 + wr * WMT + i * 16 + quad * 4 + r;
                    Cp[(size_t)m * ldc + n] = acc[i][j][r];
                }
            }
    } else if constexpr (MODE == 2) {
        // fused LSTM cell: fragments j=0..3 are gates i,f,g,o of column jj
        float bv[WN];
#pragma unroll
        for (int j = 0; j < WN; ++j) bv[j] = INITC ? 0.0f : bias[n0 + j * 16 + l16];
        const int jj = (n0 >> 2) + l16;   // n0 = bx*64 -> j base = bx*16
#pragma unroll
        for (int i = 0; i < WM; ++i) {
#pragma unroll
            for (int r = 0; r < 4; ++r) {
                const int m = m0 + wr * WMT + i * 16 + quad * 4 + r;
                float gi = acc[i][0][r] + bv[0];
                float gf = acc[i][1][r] + bv[1];
                float gg = acc[i][2][r] + bv[2];
                float go = acc[i][3][r] + bv[3];
                float i_ = 1.0f / (1.0f + expf(-gi));
                float f_ = 1.0f / (1.0f + expf(-gf));
                float g_ = tanhf(gg);
                float o_ = 1.0f / (1.0f + expf(-go));
                const size_t ci = (size_t)m * H_DIM + jj;
                float cn = f_ * cstate[ci] + i_ * g_;
                cstate[ci] = cn;
                hdst[(size_t)m * IN_LD + (D_IN + E_EMB) + jj] = f2b(o_ * tanhf(cn));
            }
        }
    } else if constexpr (MODE == 4) {
        _Float16* Ch = (_Float16*)C;
        float bv[WN];
#pragma unroll
        for (int j = 0; j < WN; ++j) bv[j] = bias[n0 + wc * WNT + j * 16 + l16];
#pragma unroll
        for (int i = 0; i < WM; ++i) {
            float rm[4] = {-1e30f, -1e30f, -1e30f, -1e30f};
            float rs[4] = {0.f, 0.f, 0.f, 0.f};
#pragma unroll
            for (int j = 0; j < WN; ++j)
#pragma unroll
                for (int r = 0; r < 4; ++r)
                    rm[r] = fmaxf(rm[r], acc[i][j][r] + bv[j]);
#pragma unroll
            for (int j = 0; j < WN; ++j) {
                const int n = n0 + wc * WNT + j * 16 + l16;
#pragma unroll
                for (int r = 0; r < 4; ++r) {
                    const int m = m0 + wr * WMT + i * 16 + quad * 4 + r;
                    float z = acc[i][j][r] + bv[j];
                    rs[r] += __expf(z - rm[r]);
                    Ch[(size_t)m * ldc + n] = (_Float16)z;
                }
            }
            // merge (max,sum) across the 16 l16-lanes of this quad
#pragma unroll
            for (int mask = 1; mask < 16; mask <<= 1) {
#pragma unroll
                for (int r = 0; r < 4; ++r) {
                    float om = __shfl_xor(rm[r], mask);
                    float os = __shfl_xor(rs[r], mask);
                    float nm = fmaxf(rm[r], om);
                    rs[r] = rs[r] * __expf(rm[r] - nm) + os * __expf(om - nm);
                    rm[r] = nm;
                }
            }
            if (l16 == 0) {
                const int seg = (n0 + wc * WNT) >> 6;
#pragma unroll
                for (int r = 0; r < 4; ++r) {
                    const int m = m0 + wr * WMT + i * 16 + quad * 4 + r;
                    stats[(size_t)m * SEGSTRIDE + seg] = make_float2(rm[r], rs[r]);
                }
            }
        }
    } else {
        float bv[WN];
#pragma unroll
        for (int j = 0; j < WN; ++j) bv[j] = bias[n0 + wc * WNT + j * 16 + l16];
#pragma unroll
        for (int i = 0; i < WM; ++i)
#pragma unroll
            for (int j = 0; j < WN; ++j) {
                const int n = n0 + wc * WNT + j * 16 + l16;
#pragma unroll
                for (int r = 0; r < 4; ++r) {
                    const int m = m0 + wr * WMT + i * 16 + quad * 4 + r;
                    C[(size_t)m * ldc + n] = acc[i][j][r] + bv[j];
                }
            }
    }
}

// ---------------------------------------------------------------------------
// per-launch prep: bf16 weight packs + Abuf init + c zero.
// Wx16 (2048x512) = x-part of W_ih; Wg (2048x768) = [emb|h]-part weights.
// Both row-REORDERED for the fused-LSTM gates GEMM:
//   row' = (j>>4)*64 + gate*16 + (j&15), orig row g = gate*512 + j
__global__ __launch_bounds__(256) void k_prep(
    const float* __restrict__ x, const float* __restrict__ emb_table,
    const float* __restrict__ W_ih, const float* __restrict__ W_hh,
    const float* __restrict__ b_ih, const float* __restrict__ b_hh,
    const float* __restrict__ W_out,
    short* __restrict__ Abuf, short* __restrict__ Wg, short* __restrict__ Wx16,
    float* __restrict__ bsum, short* __restrict__ Wout16, float* __restrict__ c)
{
    const int idx0 = blockIdx.x * 256 + threadIdx.x;
    const int gs = gridDim.x * 256;
    const float4* W4 = (const float4*)W_out;
    for (int i = idx0; i < V_DIM * H_DIM / 4; i += gs) {
        float4 v = W4[i];
        short4 o;
        o.x = f2b(v.x); o.y = f2b(v.y); o.z = f2b(v.z); o.w = f2b(v.w);
        ((short4*)Wout16)[i] = o;
    }
    // Wg: per-step K = [emb(256) | h(512)]
    for (int i = idx0; i < G_DIM * KG; i += gs) {
        int rp = i / KG, k = i - rp * KG;
        int j = ((rp >> 6) << 4) | (rp & 15);
        int gate = (rp >> 4) & 3;
        int g = gate * H_DIM + j;
        float v = (k < E_EMB) ? W_ih[(size_t)g * (D_IN + E_EMB) + D_IN + k]
                              : W_hh[(size_t)g * H_DIM + (k - E_EMB)];
        Wg[i] = f2b(v);
    }
    // Wx16: constant x-part of W_ih
    for (int i = idx0; i < G_DIM * D_IN; i += gs) {
        int rp = i / D_IN, k = i - rp * D_IN;
        int j = ((rp >> 6) << 4) | (rp & 15);
        int gate = (rp >> 4) & 3;
        int g = gate * H_DIM + j;
        Wx16[i] = f2b(W_ih[(size_t)g * (D_IN + E_EMB) + k]);
    }
    for (int i = idx0; i < G_DIM; i += gs) {
        int j = ((i >> 6) << 4) | (i & 15);
        int gate = (i >> 4) & 3;
        int g = gate * H_DIM + j;
        bsum[i] = b_ih[g] + b_hh[g];
    }
    for (int i = idx0; i < N_ROWS * IN_LD; i += gs) {
        int n = i / IN_LD, col = i - n * IN_LD;
        float v;
        if (col < D_IN)              v = x[(size_t)n * D_IN + col];
        else if (col < D_IN + E_EMB) v = emb_table[(size_t)OOV_ID * E_EMB + (col - D_IN)];
        else                         v = 0.0f;
        Abuf[i] = f2b(v);
    }
    for (int i = idx0; i < N_ROWS * H_DIM; i += gs) c[i] = 0.0f;
}

// ---------------------------------------------------------------------------
// emb_T[e][v] = bf16(emb_table[v][e])  (256 x 32000)
__global__ __launch_bounds__(256) void k_trans(const float* __restrict__ emb,
                                               short* __restrict__ embT)
{
    __shared__ float tile[64][65];
    const int v0 = blockIdx.x * 64, e0 = blockIdx.y * 64;
    const int tid = threadIdx.x;
#pragma unroll
    for (int i = 0; i < 16; ++i) {
        int idx = tid + i * 256;
        int vr = idx >> 6, ec = idx & 63;
        tile[vr][ec] = emb[(size_t)(v0 + vr) * E_EMB + e0 + ec];
    }
    __syncthreads();
#pragma unroll
    for (int i = 0; i < 16; ++i) {
        int idx = tid + i * 256;
        int er = idx >> 6, vc = idx & 63;
        embT[(size_t)(e0 + er) * V_DIM + v0 + vc] = f2b(tile[vc][er]);
    }
}

// ---------------------------------------------------------------------------
// reduce split-K emb partials -> bf16 into Abuf[:,512:768)
__global__ __launch_bounds__(256) void k_embred(const float* __restrict__ ep,
                                                short* __restrict__ Abuf)
{
    int idx = blockIdx.x * 256 + threadIdx.x;   // 512*256 total
    int n = idx >> 8, e = idx & 255;
    float s0 = 0.f, s1 = 0.f;
#pragma unroll 2
    for (int z = 0; z < EMB_SPLIT; z += 2) {
        s0 += ep[((size_t)z * N_ROWS + n) * E_EMB + e];
        s1 += ep[((size_t)(z + 1) * N_ROWS + n) * E_EMB + e];
    }
    Abuf[(size_t)n * IN_LD + D_IN + e] = f2b(s0 + s1);
}

// ---------------------------------------------------------------------------
// fused lse + streaming finish: each block folds the row's 500 (max,sumexp)
// stats partials to lse (L2-hot, redundant across the 8 x-blocks), then
// out = fp16 z - lse (fp32) + bf16 probs into `last`.
__global__ __launch_bounds__(256) void k_finish(const _Float16* __restrict__ zbuf,
                                                float* __restrict__ out,
                                                short* __restrict__ last,
                                                const float2* __restrict__ stats,
                                                int step, int feed)
{
    const int n = blockIdx.y;
    const int tid = threadIdx.x;
    const int lane = tid & 63, wid = tid >> 6;
    __shared__ float redm[4], reds[4];

    float m = -1e30f, s = 0.0f;
    for (int sg = tid; sg < V_DIM / 64; sg += 256) {
        float2 p = stats[(size_t)n * SEGSTRIDE + sg];
        float nm = fmaxf(m, p.x);
        s = s * __expf(m - nm) + p.y * __expf(p.x - nm);
        m = nm;
    }
#pragma unroll
    for (int off = 32; off > 0; off >>= 1) {
        float m2 = __shfl_down(m, off), s2 = __shfl_down(s, off);
        float nm = fmaxf(m, m2);
        s = s * __expf(m - nm) + s2 * __expf(m2 - nm);
        m = nm;
    }
    if (lane == 0) { redm[wid] = m; reds[wid] = s; }
    __syncthreads();
    float fm = redm[0], fs = reds[0];
#pragma unroll
    for (int w = 1; w < 4; ++w) {
        float nm = fmaxf(fm, redm[w]);
        fs = fs * __expf(fm - nm) + reds[w] * __expf(redm[w] - nm);
        fm = nm;
    }
    const float l = fm + __logf(fs);

    const f16x8* zr = (const f16x8*)(zbuf + (size_t)n * V_DIM);
    float4* row4 = (float4*)(out + ((size_t)n * K_STEPS + step) * V_DIM);
    bf16x8* prow = (bf16x8*)(last + (size_t)n * V_DIM);
#pragma unroll
    for (int it = 0; it < 2; ++it) {
        const int slot = tid + it * 256;
        if (slot < 500) {
            const int cidx = blockIdx.x * 500 + slot;
            f16x8 zv = zr[cidx];
            float lp[8];
#pragma unroll
            for (int k = 0; k < 8; ++k) lp[k] = (float)zv[k] - l;
            row4[cidx * 2]     = make_float4(lp[0], lp[1], lp[2], lp[3]);
            row4[cidx * 2 + 1] = make_float4(lp[4], lp[5], lp[6], lp[7]);
            if (feed) {
                bf16x8 p;
#pragma unroll
                for (int k = 0; k < 8; ++k) p[k] = f2b(__expf(lp[k]));
                prow[cidx] = p;
            }
        }
    }
}

// ---------------------------------------------------------------------------
extern "C" void kernel_launch(void* const* d_in, const int* in_sizes, int n_in,
                              void* d_out, int out_size, void* d_ws, size_t ws_size,
                              hipStream_t stream) {
    (void)in_sizes; (void)n_in; (void)out_size; (void)ws_size;
    const float* x       = (const float*)d_in[0];
    const float* emb_tab = (const float*)d_in[2];
    const float* W_ih    = (const float*)d_in[3];
    const float* b_ih    = (const float*)d_in[4];
    const float* W_hh    = (const float*)d_in[5];
    const float* b_hh    = (const float*)d_in[6];
    const float* W_out   = (const float*)d_in[7];
    const float* b_out   = (const float*)d_in[8];
    float* out = (float*)d_out;

    // workspace carve (~130 MB; ws is ~1 GB per harness poison fill)
    char* ws = (char*)d_ws;
    short* Abuf   = (short*)ws;  ws += (size_t)N_ROWS * IN_LD * sizeof(short);
    float* c      = (float*)ws;  ws += (size_t)N_ROWS * H_DIM * sizeof(float);
    short* last   = (short*)ws;  ws += (size_t)N_ROWS * V_DIM * sizeof(short);
    short* Wout16 = (short*)ws;  ws += (size_t)V_DIM * H_DIM * sizeof(short);
    short* Wg     = (short*)ws;  ws += (size_t)G_DIM * KG * sizeof(short);
    short* Wx16   = (short*)ws;  ws += (size_t)G_DIM * D_IN * sizeof(short);
    float* bsum   = (float*)ws;  ws += (size_t)G_DIM * sizeof(float);
    float* gates0 = (float*)ws;  ws += (size_t)N_ROWS * G_DIM * sizeof(float);
    short* embT   = (short*)ws;  ws += (size_t)E_EMB * V_DIM * sizeof(short);
    float2* stats = (float2*)ws; ws += (size_t)N_ROWS * SEGSTRIDE * sizeof(float2);
    ws = (char*)(((size_t)ws + 255) & ~(size_t)255);
    // scratch union: zbuf (32.8 MB) / emb partials (26.2 MB) — disjoint lifetimes
    _Float16* zbuf = (_Float16*)ws;
    float* epart   = (float*)ws;
    ws += (size_t)EMB_SPLIT * N_ROWS * E_EMB * sizeof(float);

    k_prep<<<2048, 256, 0, stream>>>(x, emb_tab, W_ih, W_hh, b_ih, b_hh, W_out,
                                     Abuf, Wg, Wx16, bsum, Wout16, c);
    k_trans<<<dim3(V_DIM / 64, E_EMB / 64), 256, 0, stream>>>(emb_tab, embT);
    // gates0 = x(512x512) @ Wx16(2048x512)^T + bsum   (constant across steps)
    k_gemm<64, 64, 4, 1, 0, 0><<<dim3(G_DIM / 64, N_ROWS / 64, 1), 256, 0, stream>>>(
        Abuf, IN_LD, Wx16, D_IN, bsum, gates0, G_DIM, D_IN, nullptr, nullptr, nullptr);

    for (int t = 0; t < K_STEPS; ++t) {
        if (t > 0) {
            // epart[z] = last(512x32000) @ embT(256x32000)^T chunk, no atomics
            k_gemm<128, 256, 2, 4, 3, 0><<<dim3(1, N_ROWS / 128, EMB_SPLIT), 512, 0, stream>>>(
                last, V_DIM, embT, V_DIM, nullptr, epart, E_EMB, EMB_CHUNK,
                nullptr, nullptr, nullptr);
            k_embred<<<N_ROWS * E_EMB / 256, 256, 0, stream>>>(epart, Abuf);
        }
        // gates GEMM (K=768, acc init from gates0) + fused LSTM -> c, h
        k_gemm<64, 64, 4, 1, 2, 1><<<dim3(G_DIM / 64, N_ROWS / 64, 1), 256, 0, stream>>>(
            Abuf + D_IN, IN_LD, Wg, KG, nullptr, gates0, G_DIM, KG, nullptr, c, Abuf);
        // logits: h(512x512) @ Wout16(32000x512)^T + b_out -> zbuf fp16 + stats
        k_gemm<128, 128, 2, 2, 4, 0><<<dim3(V_DIM / 128, N_ROWS / 128, 1), 256, 0, stream>>>(
            Abuf + (D_IN + E_EMB), IN_LD, Wout16, H_DIM, b_out,
            (float*)zbuf, V_DIM, H_DIM, stats, nullptr, nullptr);
        const int feed = (t < K_STEPS - 1) ? 1 : 0;
        k_finish<<<dim3(8, N_ROWS), 256, 0, stream>>>(zbuf, out, last, stats, t, feed);
    }
}

// Round 7
// 670.263 us; speedup vs baseline: 1.0705x; 1.0705x over previous
//
#include <hip/hip_runtime.h>
#include <hip/hip_bf16.h>
#include <math.h>

// Problem constants
#define N_ROWS 512      // B*S
#define D_IN   512
#define E_EMB  256
#define H_DIM  512
#define G_DIM  2048
#define V_DIM  32000
#define IN_LD  1280     // Abuf row: [ x(512) | emb(256) | h(512) ]
#define K_STEPS 4
#define OOV_ID 1
#define TBK 64
#define EMB_SPLIT 50
#define EMB_CHUNK 640   // 50*640 = 32000
#define SEGSTRIDE 512   // stats row stride (500 used)

typedef __attribute__((ext_vector_type(4))) float f32x4;
typedef __attribute__((ext_vector_type(8))) short bf16x8;
typedef __attribute__((ext_vector_type(8))) _Float16 f16x8;

__device__ inline short f2b(float v) {
    __hip_bfloat16 h = __float2bfloat16(v);
    return *reinterpret_cast<short*>(&h);
}

// async global->LDS, 16B per lane; dest = ldsbase + lane*16 (wave-uniform base)
__device__ inline void gload_lds(const short* g, short* l) {
    __builtin_amdgcn_global_load_lds(
        (const __attribute__((address_space(1))) void*)g,
        (__attribute__((address_space(3))) void*)l, 16, 0, 0);
}

// ---------------------------------------------------------------------------
// MFMA GEMM: C(MxN) = A(MxK,bf16 rm) @ B(NxK,bf16 rm)^T [+bias]
// WR_ x WC_ waves (64*WR_*WC_ threads). global_load_lds staging, XOR-swizzled
// LDS chunks (proven 2-barrier structure; only tile/wave geometry templated).
// MODE 0: C = acc + bias[n]
// MODE 2: fused LSTM epilogue (requires WC_==1, WNT==64): the 4 N-fragments
//         of a thread are gates i,f,g,o of one j (Wg rows pre-reordered as
//         row' = (j>>4)*64 + gate*16 + (j&15)). Updates cstate, writes bf16 h
//         into hdst (Abuf h-region).
// MODE 3: split-K partial store: C[(bz*N_ROWS + m)*ldc + n] = acc  (no atomics)
// MODE 4: z = acc + bias stored as fp16 into C, plus per-64-col (max,sumexp)
//         stats partials (requires WNT==64).
// MODE 5: MODE 3 epilogue + fused softmax-finish A-staging: A is fp16 z
//         (ld=lda). Per A-element (read exactly once across the split-K grid):
//         lp = z - lsep[row]; write lp (logp) to outdst; stage bf16 exp(lp)
//         into the same swizzled LDS slot gload_lds would have used.
template<int TBM, int TBN, int WR_, int WC_, int MODE>
__global__ __launch_bounds__(WR_ * WC_ * 64) void k_gemm(
    const short* __restrict__ A, int lda,
    const short* __restrict__ B, int ldb,
    const float* __restrict__ bias,
    float* __restrict__ C, size_t ldc, int Kc,
    float2* __restrict__ stats,
    float* __restrict__ cstate, short* __restrict__ hdst,
    float* __restrict__ outdst, size_t ldout, const float* __restrict__ lsep)
{
    constexpr int NW = WR_ * WC_;
    constexpr int WMT = TBM / WR_, WNT = TBN / WC_;
    constexpr int WM = WMT / 16, WN = WNT / 16;
    __shared__ short As[TBM * 64];
    __shared__ short Bs[TBN * 64];
    const int tid = threadIdx.x;
    const int lane = tid & 63, wid = tid >> 6;
    const int wr = wid % WR_, wc = wid / WR_;
    const int quad = lane >> 4, l16 = lane & 15;
    const int m0 = blockIdx.y * TBM, n0 = blockIdx.x * TBN;
    const int kbase = blockIdx.z * Kc;
    // staging lane geometry: 8 rows/instr, 8 chunks of 8 bf16 per row, XOR swizzle
    const int lrow = lane >> 3;
    const int lsw  = ((lane & 7) ^ lrow) * 8;

    f32x4 acc[WM][WN];
#pragma unroll
    for (int i = 0; i < WM; ++i)
#pragma unroll
        for (int j = 0; j < WN; ++j)
#pragma unroll
            for (int r = 0; r < 4; ++r) acc[i][j][r] = 0.0f;

    for (int kt = 0; kt < Kc; kt += TBK) {
        const int k0 = kbase + kt;
        if constexpr (MODE == 5) {
            // B first (async, in flight under the A VALU work)
#pragma unroll
            for (int ch = wid; ch < TBN / 8; ch += NW)
                gload_lds(&B[(size_t)(n0 + ch * 8 + lrow) * ldb + k0 + lsw], &Bs[ch * 512]);
            const _Float16* Z = (const _Float16*)A;
#pragma unroll
            for (int ch = wid; ch < TBM / 8; ch += NW) {
                const int row = m0 + ch * 8 + lrow;
                const int col = k0 + lsw;
                f16x8 zv = *(const f16x8*)&Z[(size_t)row * lda + col];
                const float l = lsep[row];
                float lp[8];
#pragma unroll
                for (int q = 0; q < 8; ++q) lp[q] = (float)zv[q] - l;
                float4* od = (float4*)&outdst[(size_t)row * ldout + col];
                od[0] = make_float4(lp[0], lp[1], lp[2], lp[3]);
                od[1] = make_float4(lp[4], lp[5], lp[6], lp[7]);
                bf16x8 p;
#pragma unroll
                for (int q = 0; q < 8; ++q) p[q] = f2b(__expf(lp[q]));
                *(bf16x8*)&As[ch * 512 + lane * 8] = p;
            }
        } else {
#pragma unroll
            for (int ch = wid; ch < TBM / 8; ch += NW)
                gload_lds(&A[(size_t)(m0 + ch * 8 + lrow) * lda + k0 + lsw], &As[ch * 512]);
#pragma unroll
            for (int ch = wid; ch < TBN / 8; ch += NW)
                gload_lds(&B[(size_t)(n0 + ch * 8 + lrow) * ldb + k0 + lsw], &Bs[ch * 512]);
        }
        __syncthreads();
#pragma unroll
        for (int ks = 0; ks < 2; ++ks) {
            bf16x8 af[WM], bfv[WN];
#pragma unroll
            for (int i = 0; i < WM; ++i) {
                int rr = wr * WMT + i * 16 + l16;
                af[i] = *(const bf16x8*)&As[rr * 64 + (((ks * 4 + quad) ^ (l16 & 7)) * 8)];
            }
#pragma unroll
            for (int j = 0; j < WN; ++j) {
                int rr = wc * WNT + j * 16 + l16;
                bfv[j] = *(const bf16x8*)&Bs[rr * 64 + (((ks * 4 + quad) ^ (l16 & 7)) * 8)];
            }
#pragma unroll
            for (int i = 0; i < WM; ++i)
#pragma unroll
                for (int j = 0; j < WN; ++j)
                    acc[i][j] = __builtin_amdgcn_mfma_f32_16x16x32_bf16(af[i], bfv[j], acc[i][j], 0, 0, 0);
        }
        __syncthreads();
    }

    // epilogue. C frag layout: row = quad*4 + reg, col = l16
    if constexpr (MODE == 3 || MODE == 5) {
        float* Cp = C + (size_t)blockIdx.z * N_ROWS * ldc;
#pragma unroll
        for (int i = 0; i < WM; ++i)
#pragma unroll
            for (int j = 0; j < WN; ++j) {
                const int n = n0 + wc * WNT + j * 16 + l16;
#pragma unroll
                for (int r = 0; r < 4; ++r) {
                    const int m = m0 + wr * WMT + i * 16 + quad * 4 + r;
                    Cp[(size_t)m * ldc + n] = acc[i][j][r];
                }
            }
    } else if constexpr (MODE == 2) {
        // fused LSTM cell: fragments j=0..3 are gates i,f,g,o of column jj
        float bv[WN];
#pragma unroll
        for (int j = 0; j < WN; ++j) bv[j] = bias[n0 + j * 16 + l16];
        const int jj = (n0 >> 2) + l16;   // n0 = bx*64 -> j base = bx*16
#pragma unroll
        for (int i = 0; i < WM; ++i) {
#pragma unroll
            for (int r = 0; r < 4; ++r) {
                const int m = m0 + wr * WMT + i * 16 + quad * 4 + r;
                float gi = acc[i][0][r] + bv[0];
                float gf = acc[i][1][r] + bv[1];
                float gg = acc[i][2][r] + bv[2];
                float go = acc[i][3][r] + bv[3];
                float i_ = 1.0f / (1.0f + expf(-gi));
                float f_ = 1.0f / (1.0f + expf(-gf));
                float g_ = tanhf(gg);
                float o_ = 1.0f / (1.0f + expf(-go));
                const size_t ci = (size_t)m * H_DIM + jj;
                float cn = f_ * cstate[ci] + i_ * g_;
                cstate[ci] = cn;
                hdst[(size_t)m * IN_LD + (D_IN + E_EMB) + jj] = f2b(o_ * tanhf(cn));
            }
        }
    } else if constexpr (MODE == 4) {
        _Float16* Ch = (_Float16*)C;
        float bv[WN];
#pragma unroll
        for (int j = 0; j < WN; ++j) bv[j] = bias[n0 + wc * WNT + j * 16 + l16];
#pragma unroll
        for (int i = 0; i < WM; ++i) {
            float rm[4] = {-1e30f, -1e30f, -1e30f, -1e30f};
            float rs[4] = {0.f, 0.f, 0.f, 0.f};
#pragma unroll
            for (int j = 0; j < WN; ++j)
#pragma unroll
                for (int r = 0; r < 4; ++r)
                    rm[r] = fmaxf(rm[r], acc[i][j][r] + bv[j]);
#pragma unroll
            for (int j = 0; j < WN; ++j) {
                const int n = n0 + wc * WNT + j * 16 + l16;
#pragma unroll
                for (int r = 0; r < 4; ++r) {
                    const int m = m0 + wr * WMT + i * 16 + quad * 4 + r;
                    float z = acc[i][j][r] + bv[j];
                    rs[r] += __expf(z - rm[r]);
                    Ch[(size_t)m * ldc + n] = (_Float16)z;
                }
            }
            // merge (max,sum) across the 16 l16-lanes of this quad
#pragma unroll
            for (int mask = 1; mask < 16; mask <<= 1) {
#pragma unroll
                for (int r = 0; r < 4; ++r) {
                    float om = __shfl_xor(rm[r], mask);
                    float os = __shfl_xor(rs[r], mask);
                    float nm = fmaxf(rm[r], om);
                    rs[r] = rs[r] * __expf(rm[r] - nm) + os * __expf(om - nm);
                    rm[r] = nm;
                }
            }
            if (l16 == 0) {
                const int seg = (n0 + wc * WNT) >> 6;
#pragma unroll
                for (int r = 0; r < 4; ++r) {
                    const int m = m0 + wr * WMT + i * 16 + quad * 4 + r;
                    stats[(size_t)m * SEGSTRIDE + seg] = make_float2(rm[r], rs[r]);
                }
            }
        }
    } else {
        float bv[WN];
#pragma unroll
        for (int j = 0; j < WN; ++j) bv[j] = bias[n0 + wc * WNT + j * 16 + l16];
#pragma unroll
        for (int i = 0; i < WM; ++i)
#pragma unroll
            for (int j = 0; j < WN; ++j) {
                const int n = n0 + wc * WNT + j * 16 + l16;
#pragma unroll
                for (int r = 0; r < 4; ++r) {
                    const int m = m0 + wr * WMT + i * 16 + quad * 4 + r;
                    C[(size_t)m * ldc + n] = acc[i][j][r] + bv[j];
                }
            }
    }
}

// ---------------------------------------------------------------------------
// per-launch prep: bf16 weight packs + Abuf init + c zero.
// Wg/bsum are REORDERED for the fused-LSTM gates GEMM:
//   row' = (j>>4)*64 + gate*16 + (j&15), orig row g = gate*512 + j
__global__ __launch_bounds__(256) void k_prep(
    const float* __restrict__ x, const float* __restrict__ emb_table,
    const float* __restrict__ W_ih, const float* __restrict__ W_hh,
    const float* __restrict__ b_ih, const float* __restrict__ b_hh,
    const float* __restrict__ W_out,
    short* __restrict__ Abuf, short* __restrict__ Wg, float* __restrict__ bsum,
    short* __restrict__ Wout16, float* __restrict__ c)
{
    const int idx0 = blockIdx.x * 256 + threadIdx.x;
    const int gs = gridDim.x * 256;
    const float4* W4 = (const float4*)W_out;
    for (int i = idx0; i < V_DIM * H_DIM / 4; i += gs) {
        float4 v = W4[i];
        short4 o;
        o.x = f2b(v.x); o.y = f2b(v.y); o.z = f2b(v.z); o.w = f2b(v.w);
        ((short4*)Wout16)[i] = o;
    }
    for (int i = idx0; i < G_DIM * IN_LD; i += gs) {
        int rp = i / IN_LD, k = i - rp * IN_LD;
        int j = ((rp >> 6) << 4) | (rp & 15);
        int gate = (rp >> 4) & 3;
        int g = gate * H_DIM + j;
        float v = (k < D_IN + E_EMB) ? W_ih[(size_t)g * (D_IN + E_EMB) + k]
                                     : W_hh[(size_t)g * H_DIM + (k - (D_IN + E_EMB))];
        Wg[i] = f2b(v);
    }
    for (int i = idx0; i < G_DIM; i += gs) {
        int j = ((i >> 6) << 4) | (i & 15);
        int gate = (i >> 4) & 3;
        int g = gate * H_DIM + j;
        bsum[i] = b_ih[g] + b_hh[g];
    }
    for (int i = idx0; i < N_ROWS * IN_LD; i += gs) {
        int n = i / IN_LD, col = i - n * IN_LD;
        float v;
        if (col < D_IN)              v = x[(size_t)n * D_IN + col];
        else if (col < D_IN + E_EMB) v = emb_table[(size_t)OOV_ID * E_EMB + (col - D_IN)];
        else                         v = 0.0f;
        Abuf[i] = f2b(v);
    }
    for (int i = idx0; i < N_ROWS * H_DIM; i += gs) c[i] = 0.0f;
}

// ---------------------------------------------------------------------------
// emb_T[e][v] = bf16(emb_table[v][e])  (256 x 32000)
__global__ __launch_bounds__(256) void k_trans(const float* __restrict__ emb,
                                               short* __restrict__ embT)
{
    __shared__ float tile[64][65];
    const int v0 = blockIdx.x * 64, e0 = blockIdx.y * 64;
    const int tid = threadIdx.x;
#pragma unroll
    for (int i = 0; i < 16; ++i) {
        int idx = tid + i * 256;
        int vr = idx >> 6, ec = idx & 63;
        tile[vr][ec] = emb[(size_t)(v0 + vr) * E_EMB + e0 + ec];
    }
    __syncthreads();
#pragma unroll
    for (int i = 0; i < 16; ++i) {
        int idx = tid + i * 256;
        int er = idx >> 6, vc = idx & 63;
        embT[(size_t)(e0 + er) * V_DIM + v0 + vc] = f2b(tile[vc][er]);
    }
}

// ---------------------------------------------------------------------------
// reduce split-K emb partials -> bf16 into Abuf[:,512:768)
__global__ __launch_bounds__(256) void k_embred(const float* __restrict__ ep,
                                                short* __restrict__ Abuf)
{
    int idx = blockIdx.x * 256 + threadIdx.x;   // 512*256 total
    int n = idx >> 8, e = idx & 255;
    float s0 = 0.f, s1 = 0.f;
#pragma unroll 2
    for (int z = 0; z < EMB_SPLIT; z += 2) {
        s0 += ep[((size_t)z * N_ROWS + n) * E_EMB + e];
        s1 += ep[((size_t)(z + 1) * N_ROWS + n) * E_EMB + e];
    }
    Abuf[(size_t)n * IN_LD + D_IN + e] = f2b(s0 + s1);
}

// ---------------------------------------------------------------------------
// lse[n] = logsumexp over the GEMM-emitted 500 segment stats. One wave per row.
__global__ __launch_bounds__(256) void k_lse(const float2* __restrict__ stats,
                                             float* __restrict__ lse)
{
    const int tid = threadIdx.x;
    const int lane = tid & 63, wid = tid >> 6;
    const int n = blockIdx.x * 4 + wid;

    float m = -1e30f, s = 0.0f;
    for (int sg = lane; sg < V_DIM / 64; sg += 64) {      // 500 segs, <=8 iters
        float2 p = stats[(size_t)n * SEGSTRIDE + sg];
        float nm = fmaxf(m, p.x);
        s = s * __expf(m - nm) + p.y * __expf(p.x - nm);
        m = nm;
    }
#pragma unroll
    for (int mask = 32; mask > 0; mask >>= 1) {
        float om = __shfl_xor(m, mask);
        float os = __shfl_xor(s, mask);
        float nm = fmaxf(m, om);
        s = s * __expf(m - nm) + os * __expf(om - nm);
        m = nm;
    }
    if (lane == 0) lse[n] = m + __logf(s);
}

// ---------------------------------------------------------------------------
// final-step finish: out = fp16 z - lse[row] (fp32). No prob feed.
__global__ __launch_bounds__(256) void k_finish(const _Float16* __restrict__ zbuf,
                                                float* __restrict__ out,
                                                const float* __restrict__ lse,
                                                int step)
{
    const int n = blockIdx.y;
    const float l = lse[n];
    const f16x8* zr = (const f16x8*)(zbuf + (size_t)n * V_DIM);
    float4* row4 = (float4*)(out + ((size_t)n * K_STEPS + step) * V_DIM);
#pragma unroll
    for (int it = 0; it < 2; ++it) {
        const int slot = threadIdx.x + it * 256;
        if (slot < 500) {
            const int cidx = blockIdx.x * 500 + slot;
            f16x8 zv = zr[cidx];
            float lp[8];
#pragma unroll
            for (int k = 0; k < 8; ++k) lp[k] = (float)zv[k] - l;
            row4[cidx * 2]     = make_float4(lp[0], lp[1], lp[2], lp[3]);
            row4[cidx * 2 + 1] = make_float4(lp[4], lp[5], lp[6], lp[7]);
        }
    }
}

// ---------------------------------------------------------------------------
extern "C" void kernel_launch(void* const* d_in, const int* in_sizes, int n_in,
                              void* d_out, int out_size, void* d_ws, size_t ws_size,
                              hipStream_t stream) {
    (void)in_sizes; (void)n_in; (void)out_size; (void)ws_size;
    const float* x       = (const float*)d_in[0];
    const float* emb_tab = (const float*)d_in[2];
    const float* W_ih    = (const float*)d_in[3];
    const float* b_ih    = (const float*)d_in[4];
    const float* W_hh    = (const float*)d_in[5];
    const float* b_hh    = (const float*)d_in[6];
    const float* W_out   = (const float*)d_in[7];
    const float* b_out   = (const float*)d_in[8];
    float* out = (float*)d_out;

    // workspace carve (~160 MB; ws is ~1 GB per harness poison fill)
    // NOTE: zbuf and epart are now BOTH live during the MODE-5 emb GEMM
    // (it reads zbuf while writing epart) -> separate allocations.
    char* ws = (char*)d_ws;
    short* Abuf   = (short*)ws;  ws += (size_t)N_ROWS * IN_LD * sizeof(short);
    float* c      = (float*)ws;  ws += (size_t)N_ROWS * H_DIM * sizeof(float);
    short* Wout16 = (short*)ws;  ws += (size_t)V_DIM * H_DIM * sizeof(short);
    short* Wg     = (short*)ws;  ws += (size_t)G_DIM * IN_LD * sizeof(short);
    float* bsum   = (float*)ws;  ws += (size_t)G_DIM * sizeof(float);
    short* embT   = (short*)ws;  ws += (size_t)E_EMB * V_DIM * sizeof(short);
    float2* stats = (float2*)ws; ws += (size_t)N_ROWS * SEGSTRIDE * sizeof(float2);
    float* lse    = (float*)ws;  ws += (size_t)N_ROWS * sizeof(float);
    ws = (char*)(((size_t)ws + 255) & ~(size_t)255);
    _Float16* zbuf = (_Float16*)ws; ws += (size_t)N_ROWS * V_DIM * sizeof(_Float16);
    float* epart   = (float*)ws;    ws += (size_t)EMB_SPLIT * N_ROWS * E_EMB * sizeof(float);

    k_prep<<<2048, 256, 0, stream>>>(x, emb_tab, W_ih, W_hh, b_ih, b_hh, W_out,
                                     Abuf, Wg, bsum, Wout16, c);
    k_trans<<<dim3(V_DIM / 64, E_EMB / 64), 256, 0, stream>>>(emb_tab, embT);

    for (int t = 0; t < K_STEPS; ++t) {
        if (t > 0) {
            // lse of the previous step's logits
            k_lse<<<N_ROWS / 4, 256, 0, stream>>>(stats, lse);
            // fused: logp(t-1) write + probs + emb GEMM (split-K partials)
            k_gemm<128, 256, 2, 4, 5><<<dim3(1, N_ROWS / 128, EMB_SPLIT), 512, 0, stream>>>(
                (const short*)zbuf, V_DIM, embT, V_DIM, nullptr, epart, E_EMB, EMB_CHUNK,
                nullptr, nullptr, nullptr,
                out + (size_t)(t - 1) * V_DIM, (size_t)K_STEPS * V_DIM, lse);
            k_embred<<<N_ROWS * E_EMB / 256, 256, 0, stream>>>(epart, Abuf);
        }
        // gates GEMM (full K=1280) + fused LSTM -> c, h
        k_gemm<64, 64, 4, 1, 2><<<dim3(G_DIM / 64, N_ROWS / 64, 1), 256, 0, stream>>>(
            Abuf, IN_LD, Wg, IN_LD, bsum, nullptr, 0, IN_LD, nullptr, c, Abuf,
            nullptr, 0, nullptr);
        // logits: h(512x512) @ Wout16(32000x512)^T + b_out -> zbuf fp16 + stats
        k_gemm<256, 128, 4, 2, 4><<<dim3(V_DIM / 128, N_ROWS / 256, 1), 512, 0, stream>>>(
            Abuf + (D_IN + E_EMB), IN_LD, Wout16, H_DIM, b_out,
            (float*)zbuf, V_DIM, H_DIM, stats, nullptr, nullptr,
            nullptr, 0, nullptr);
    }
    // final step: lse + plain finish (no feed)
    k_lse<<<N_ROWS / 4, 256, 0, stream>>>(stats, lse);
    k_finish<<<dim3(8, N_ROWS), 256, 0, stream>>>(zbuf, out, lse, K_STEPS - 1);
}